// Round 1
// baseline (464.948 us; speedup 1.0000x reference)
//
#include <hip/hip_runtime.h>
#include <stdint.h>

// Problem constants (reference: B=8, Q=2048, K=2048, D=512)
#define BB 8
#define QQ 2048
#define KK 2048
#define DD 512

typedef __bf16 bf16x8 __attribute__((ext_vector_type(8)));
typedef float f32x4 __attribute__((ext_vector_type(4)));

__device__ __forceinline__ unsigned short f2bf(float f) {
    union { float f; unsigned u; } x;
    x.f = f;
    unsigned r = x.u + 0x7fffu + ((x.u >> 16) & 1u);   // round-to-nearest-even
    return (unsigned short)(r >> 16);
}

// ---------------------------------------------------------------------------
// Elementwise fp32 -> bf16 convert (4 elems/thread)
// ---------------------------------------------------------------------------
__global__ __launch_bounds__(256) void cvt_f32_bf16(const float* __restrict__ in,
                                                    unsigned short* __restrict__ out) {
    size_t i = ((size_t)blockIdx.x * 256 + threadIdx.x) * 4;
    float4 f = *(const float4*)(in + i);
    uint2 u;
    u.x = (unsigned)f2bf(f.x) | ((unsigned)f2bf(f.y) << 16);
    u.y = (unsigned)f2bf(f.z) | ((unsigned)f2bf(f.w) << 16);
    *(uint2*)(out + i) = u;
}

// ---------------------------------------------------------------------------
// Tiled transpose + convert: in[R][C] fp32 -> out[C][R] bf16  (32x32 tiles)
// ---------------------------------------------------------------------------
__global__ __launch_bounds__(256) void transpose_cvt(const float* __restrict__ in,
                                                     unsigned short* __restrict__ out,
                                                     int R, int C, long inB, long outB) {
    __shared__ float t[32][33];
    const float* ip = in + (size_t)blockIdx.z * inB;
    unsigned short* op = out + (size_t)blockIdx.z * outB;
    int x = threadIdx.x & 31, y0 = threadIdx.x >> 5;   // 32 x 8
    int c0 = blockIdx.x * 32, r0 = blockIdx.y * 32;
#pragma unroll
    for (int i = 0; i < 32; i += 8)
        t[y0 + i][x] = ip[(size_t)(r0 + y0 + i) * C + c0 + x];
    __syncthreads();
#pragma unroll
    for (int i = 0; i < 32; i += 8)
        op[(size_t)(c0 + y0 + i) * R + r0 + x] = f2bf(t[x][y0 + i]);
}

// ---------------------------------------------------------------------------
// NT GEMM: C[m,n] = sum_k A[m,k]*B[n,k], 128x128 tile, BK=32, bf16 MFMA.
// AF32: A source is fp32 (converted to bf16 during LDS staging).
// OUTM: 0 = bf16 out; 1 = fp32 out with mask(-1e20)+scale epilogue; 2 = fp32 out.
// ---------------------------------------------------------------------------
template <bool AF32, int OUTM>
__global__ __launch_bounds__(256) void gemm_bt(const void* __restrict__ Aall,
                                               const unsigned short* __restrict__ Ball,
                                               void* __restrict__ Call,
                                               const int* __restrict__ maskAll,
                                               int Kred, int lda, int ldb, int ldc,
                                               long aStride, long bStride, long cStride,
                                               int maskStride, float scale) {
    const int b = blockIdx.z;
    const int m0 = blockIdx.y * 128;
    const int n0 = blockIdx.x * 128;

    __shared__ unsigned short As[128 * 32];
    __shared__ unsigned short Bs[128 * 32];

    const int tid = threadIdx.x;
    const int lane = tid & 63, wave = tid >> 6;
    const int wm = wave >> 1, wn = wave & 1;
    const int lrow = lane & 15, quad = lane >> 4;

    const int r8 = tid >> 2, c8 = (tid & 3) * 8;       // bf16 staging: 8 elems (16B)
    const int r4 = tid >> 3, c4 = (tid & 7) * 4;       // fp32 staging: 4 elems (16B)

    const unsigned short* Bb = Ball + (size_t)b * bStride + (size_t)n0 * ldb;

    f32x4 acc[4][4];
#pragma unroll
    for (int mi = 0; mi < 4; mi++)
#pragma unroll
        for (int ni = 0; ni < 4; ni++)
            acc[mi][ni] = (f32x4){0.f, 0.f, 0.f, 0.f};

    for (int kk = 0; kk < Kred; kk += 32) {
        // ---- stage A tile (128 x 32) ----
        if constexpr (AF32) {
            const float* A = (const float*)Aall + (size_t)b * aStride + (size_t)m0 * lda + kk;
#pragma unroll
            for (int j = 0; j < 4; j++) {
                int row = j * 32 + r4;
                float4 f = *(const float4*)(A + (size_t)row * lda + c4);
                uint2 u;
                u.x = (unsigned)f2bf(f.x) | ((unsigned)f2bf(f.y) << 16);
                u.y = (unsigned)f2bf(f.z) | ((unsigned)f2bf(f.w) << 16);
                *(uint2*)&As[row * 32 + c4] = u;
            }
        } else {
            const unsigned short* A =
                (const unsigned short*)Aall + (size_t)b * aStride + (size_t)m0 * lda + kk;
#pragma unroll
            for (int j = 0; j < 2; j++) {
                int row = j * 64 + r8;
                *(uint4*)&As[row * 32 + c8] = *(const uint4*)(A + (size_t)row * lda + c8);
            }
        }
        // ---- stage B tile (128 x 32) ----
        {
            const unsigned short* Bp = Bb + kk;
#pragma unroll
            for (int j = 0; j < 2; j++) {
                int row = j * 64 + r8;
                *(uint4*)&Bs[row * 32 + c8] = *(const uint4*)(Bp + (size_t)row * ldb + c8);
            }
        }
        __syncthreads();

        bf16x8 af[4], bfr[4];
#pragma unroll
        for (int i = 0; i < 4; i++)
            af[i] = *(const bf16x8*)&As[(wm * 64 + i * 16 + lrow) * 32 + quad * 8];
#pragma unroll
        for (int i = 0; i < 4; i++)
            bfr[i] = *(const bf16x8*)&Bs[(wn * 64 + i * 16 + lrow) * 32 + quad * 8];

#pragma unroll
        for (int mi = 0; mi < 4; mi++)
#pragma unroll
            for (int ni = 0; ni < 4; ni++)
                acc[mi][ni] = __builtin_amdgcn_mfma_f32_16x16x32_bf16(af[mi], bfr[ni],
                                                                      acc[mi][ni], 0, 0, 0);
        __syncthreads();
    }

    // ---- epilogue ----
    const float mval = -1e20f * scale;
#pragma unroll
    for (int mi = 0; mi < 4; mi++) {
#pragma unroll
        for (int ni = 0; ni < 4; ni++) {
            int gm = m0 + wm * 64 + mi * 16 + quad * 4;
            int gn = n0 + wn * 64 + ni * 16 + lrow;
            if constexpr (OUTM == 0) {
                unsigned short* C = (unsigned short*)Call + (size_t)b * cStride;
#pragma unroll
                for (int r = 0; r < 4; r++)
                    C[(size_t)(gm + r) * ldc + gn] = f2bf(acc[mi][ni][r]);
            } else if constexpr (OUTM == 1) {
                float* C = (float*)Call + (size_t)b * cStride;
                const int* mk = maskAll + (size_t)b * maskStride;
                bool keep = mk[gn] != 0;
#pragma unroll
                for (int r = 0; r < 4; r++)
                    C[(size_t)(gm + r) * ldc + gn] = keep ? acc[mi][ni][r] * scale : mval;
            } else {
                float* C = (float*)Call + (size_t)b * cStride;
#pragma unroll
                for (int r = 0; r < 4; r++)
                    C[(size_t)(gm + r) * ldc + gn] = acc[mi][ni][r];
            }
        }
    }
}

// ---------------------------------------------------------------------------
// Row softmax, in place: one block per row of 2048 fp32.
// ---------------------------------------------------------------------------
__global__ __launch_bounds__(256) void softmax_rows(float* __restrict__ dist) {
    float* p = dist + (size_t)blockIdx.x * 2048;
    int tid = threadIdx.x;
    float4 a = *(float4*)(p + tid * 8);
    float4 b = *(float4*)(p + tid * 8 + 4);

    float m = fmaxf(fmaxf(fmaxf(a.x, a.y), fmaxf(a.z, a.w)),
                    fmaxf(fmaxf(b.x, b.y), fmaxf(b.z, b.w)));
#pragma unroll
    for (int off = 32; off > 0; off >>= 1) m = fmaxf(m, __shfl_down(m, off));

    __shared__ float red[8];
    if ((tid & 63) == 0) red[tid >> 6] = m;
    __syncthreads();
    m = fmaxf(fmaxf(red[0], red[1]), fmaxf(red[2], red[3]));

    a.x = __expf(a.x - m); a.y = __expf(a.y - m);
    a.z = __expf(a.z - m); a.w = __expf(a.w - m);
    b.x = __expf(b.x - m); b.y = __expf(b.y - m);
    b.z = __expf(b.z - m); b.w = __expf(b.w - m);

    float s = a.x + a.y + a.z + a.w + b.x + b.y + b.z + b.w;
#pragma unroll
    for (int off = 32; off > 0; off >>= 1) s += __shfl_down(s, off);
    if ((tid & 63) == 0) red[4 + (tid >> 6)] = s;
    __syncthreads();
    float inv = 1.0f / (red[4] + red[5] + red[6] + red[7]);

    a.x *= inv; a.y *= inv; a.z *= inv; a.w *= inv;
    b.x *= inv; b.y *= inv; b.z *= inv; b.w *= inv;
    *(float4*)(p + tid * 8) = a;
    *(float4*)(p + tid * 8 + 4) = b;
}

// ---------------------------------------------------------------------------
extern "C" void kernel_launch(void* const* d_in, const int* in_sizes, int n_in,
                              void* d_out, int out_size, void* d_ws, size_t ws_size,
                              hipStream_t stream) {
    const float* q    = (const float*)d_in[0];   // [B,Q,D]
    const float* k    = (const float*)d_in[1];   // [B,K,D]
    const float* v    = (const float*)d_in[2];   // [B,K,D]
    const int*   mask = (const int*)d_in[3];     // [B,K]
    const float* W    = (const float*)d_in[4];   // [D,D]

    float* ctx  = (float*)d_out;                           // [B,Q,D]
    float* dist = ctx + (size_t)BB * QQ * DD;              // [B,Q,K]

    // workspace layout (bf16 = unsigned short), total ~64.5 MiB
    unsigned short* ws   = (unsigned short*)d_ws;
    unsigned short* Wt   = ws;                                  // [D][D]   (W^T)
    unsigned short* Qbf  = Wt  + (size_t)DD * DD;               // [B][Q][D]
    unsigned short* Kbf  = Qbf + (size_t)BB * QQ * DD;          // [B][K][D]
    unsigned short* Vt   = Kbf + (size_t)BB * KK * DD;          // [B][D][K] (V^T)
    unsigned short* qWbf = Vt  + (size_t)BB * DD * KK;          // [B][Q][D]

    const float scale = 0.044194173824159216f;  // 1/sqrt(512)

    // 1) W -> W^T bf16
    transpose_cvt<<<dim3(DD / 32, DD / 32, 1), 256, 0, stream>>>(W, Wt, DD, DD, 0, 0);
    // 2) query, key -> bf16
    cvt_f32_bf16<<<dim3((BB * QQ * DD / 4) / 256), 256, 0, stream>>>(q, Qbf);
    cvt_f32_bf16<<<dim3((BB * KK * DD / 4) / 256), 256, 0, stream>>>(k, Kbf);
    // 3) value -> V^T bf16
    transpose_cvt<<<dim3(DD / 32, KK / 32, BB), 256, 0, stream>>>(
        v, Vt, KK, DD, (long)KK * DD, (long)DD * KK);
    // 4) qW[b] = Q[b] @ W  (NT with Wt):  M=Q, N=D, Kred=D -> bf16
    gemm_bt<false, 0><<<dim3(DD / 128, QQ / 128, BB), 256, 0, stream>>>(
        Qbf, Wt, qWbf, nullptr, DD, DD, DD, DD,
        (long)QQ * DD, 0, (long)QQ * DD, 0, 0.f);
    // 5) scores[b] = qW[b] @ key[b]^T, mask + scale epilogue -> dist (fp32)
    gemm_bt<false, 1><<<dim3(KK / 128, QQ / 128, BB), 256, 0, stream>>>(
        qWbf, Kbf, dist, mask, DD, DD, DD, KK,
        (long)QQ * DD, (long)KK * DD, (long)QQ * KK, KK, scale);
    // 6) softmax rows in place
    softmax_rows<<<dim3(BB * QQ), 256, 0, stream>>>(dist);
    // 7) context[b] = dist[b] @ value[b]  (NT with Vt): M=Q, N=D, Kred=K
    gemm_bt<true, 2><<<dim3(DD / 128, QQ / 128, BB), 256, 0, stream>>>(
        dist, Vt, ctx, nullptr, KK, KK, KK, DD,
        (long)QQ * KK, (long)DD * KK, (long)QQ * DD, 0, 0.f);
}

// Round 2
// 425.101 us; speedup vs baseline: 1.0937x; 1.0937x over previous
//
#include <hip/hip_runtime.h>
#include <stdint.h>

// Problem constants (reference: B=8, Q=2048, K=2048, D=512)
#define BB 8
#define QQ 2048
#define KK 2048
#define DD 512

typedef _Float16 f16x8 __attribute__((ext_vector_type(8)));
typedef float f32x4 __attribute__((ext_vector_type(4)));

__device__ __forceinline__ unsigned short f2h(float f) {
    union { _Float16 h; unsigned short u; } x;
    x.h = (_Float16)f;
    return x.u;
}
__device__ __forceinline__ float h2f(unsigned short u) {
    union { unsigned short u; _Float16 h; } x;
    x.u = u;
    return (float)x.h;
}

// async global->LDS, 16 B per lane. lds must be wave-uniform base; HW scatters
// lane l to lds + l*16 (m97/m104 semantics).
__device__ __forceinline__ void async16(const unsigned short* g, unsigned short* l) {
    __builtin_amdgcn_global_load_lds(
        (const __attribute__((address_space(1))) unsigned int*)g,
        (__attribute__((address_space(3))) unsigned int*)l, 16, 0, 0);
}

// ---------------------------------------------------------------------------
// fp32 -> fp16 convert, 8 elems/thread
// ---------------------------------------------------------------------------
__global__ __launch_bounds__(256) void cvt_f32_f16(const float* __restrict__ in,
                                                   unsigned short* __restrict__ out) {
    size_t i = ((size_t)blockIdx.x * 256 + threadIdx.x) * 8;
    float4 a = *(const float4*)(in + i);
    float4 b = *(const float4*)(in + i + 4);
    uint4 u;
    u.x = (unsigned)f2h(a.x) | ((unsigned)f2h(a.y) << 16);
    u.y = (unsigned)f2h(a.z) | ((unsigned)f2h(a.w) << 16);
    u.z = (unsigned)f2h(b.x) | ((unsigned)f2h(b.y) << 16);
    u.w = (unsigned)f2h(b.z) | ((unsigned)f2h(b.w) << 16);
    *(uint4*)(out + i) = u;
}

// ---------------------------------------------------------------------------
// Tiled transpose + convert: in[R][C] fp32 -> out[C][R] fp16 (32x32 tiles)
// ---------------------------------------------------------------------------
__global__ __launch_bounds__(256) void transpose_cvt(const float* __restrict__ in,
                                                     unsigned short* __restrict__ out,
                                                     int R, int C, long inB, long outB) {
    __shared__ float t[32][33];
    const float* ip = in + (size_t)blockIdx.z * inB;
    unsigned short* op = out + (size_t)blockIdx.z * outB;
    int x = threadIdx.x & 31, y0 = threadIdx.x >> 5;   // 32 x 8
    int c0 = blockIdx.x * 32, r0 = blockIdx.y * 32;
#pragma unroll
    for (int i = 0; i < 32; i += 8)
        t[y0 + i][x] = ip[(size_t)(r0 + y0 + i) * C + c0 + x];
    __syncthreads();
#pragma unroll
    for (int i = 0; i < 32; i += 8)
        op[(size_t)(c0 + y0 + i) * R + r0 + x] = f2h(t[x][y0 + i]);
}

// ---------------------------------------------------------------------------
// NT GEMM: C[m,n] = sum_k A[m,k]*B[n,k], 128x128 tile, BK=32, f16 MFMA.
// AF32: A is fp32, converted during (synchronous) staging; else fp16 via
//       global_load_lds width-16 async staging.
// OUTM: 0 = f16 out; 1 = f16 out with mask(-6e4)+scale epilogue; 2 = fp32 out.
// ---------------------------------------------------------------------------
template <bool AF32, int OUTM>
__global__ __launch_bounds__(256) void gemm_bt(const void* __restrict__ Aall,
                                               const unsigned short* __restrict__ Ball,
                                               void* __restrict__ Call,
                                               const int* __restrict__ maskAll,
                                               int Kred, int lda, int ldb, int ldc,
                                               long aStride, long bStride, long cStride,
                                               int maskStride, float scale) {
    const int b = blockIdx.z;
    const int m0 = blockIdx.y * 128;
    const int n0 = blockIdx.x * 128;

    __shared__ unsigned short As[128 * 32];
    __shared__ unsigned short Bs[128 * 32];

    const int tid = threadIdx.x;
    const int lane = tid & 63, wave = tid >> 6;
    const int wm = wave >> 1, wn = wave & 1;
    const int lrow = lane & 15, quad = lane >> 4;

    // async staging: call j covers rows j*64 + tid>>2, col (tid&3)*8 (16 B)
    const int ar = tid >> 2, ac = (tid & 3) * 8;
    // fp32 staging: rows j*32 + tid>>3, col (tid&7)*4
    const int fr = tid >> 3, fc = (tid & 7) * 4;

    const unsigned short* Bb = Ball + (size_t)b * bStride + (size_t)n0 * ldb;
    unsigned short* AsW = As + wave * 512;   // wave-uniform async dst
    unsigned short* BsW = Bs + wave * 512;

    f32x4 acc[4][4];
#pragma unroll
    for (int mi = 0; mi < 4; mi++)
#pragma unroll
        for (int ni = 0; ni < 4; ni++)
            acc[mi][ni] = (f32x4){0.f, 0.f, 0.f, 0.f};

    for (int kk = 0; kk < Kred; kk += 32) {
        // ---- stage A tile (128 x 32) ----
        if constexpr (AF32) {
            const float* A = (const float*)Aall + (size_t)b * aStride + (size_t)m0 * lda + kk;
#pragma unroll
            for (int j = 0; j < 4; j++) {
                int row = j * 32 + fr;
                float4 f = *(const float4*)(A + (size_t)row * lda + fc);
                uint2 u;
                u.x = (unsigned)f2h(f.x) | ((unsigned)f2h(f.y) << 16);
                u.y = (unsigned)f2h(f.z) | ((unsigned)f2h(f.w) << 16);
                *(uint2*)&As[row * 32 + fc] = u;
            }
        } else {
            const unsigned short* A =
                (const unsigned short*)Aall + (size_t)b * aStride + (size_t)m0 * lda + kk;
#pragma unroll
            for (int j = 0; j < 2; j++)
                async16(A + (size_t)(j * 64 + ar) * lda + ac, AsW + j * 2048);
        }
        // ---- stage B tile (128 x 32) ----
        {
            const unsigned short* Bp = Bb + kk;
#pragma unroll
            for (int j = 0; j < 2; j++)
                async16(Bp + (size_t)(j * 64 + ar) * ldb + ac, BsW + j * 2048);
        }
        __syncthreads();

        f16x8 af[4], bfr[4];
#pragma unroll
        for (int i = 0; i < 4; i++)
            af[i] = *(const f16x8*)&As[(wm * 64 + i * 16 + lrow) * 32 + quad * 8];
#pragma unroll
        for (int i = 0; i < 4; i++)
            bfr[i] = *(const f16x8*)&Bs[(wn * 64 + i * 16 + lrow) * 32 + quad * 8];

#pragma unroll
        for (int mi = 0; mi < 4; mi++)
#pragma unroll
            for (int ni = 0; ni < 4; ni++)
                acc[mi][ni] = __builtin_amdgcn_mfma_f32_16x16x32_f16(af[mi], bfr[ni],
                                                                     acc[mi][ni], 0, 0, 0);
        __syncthreads();
    }

    // ---- epilogue ----
#pragma unroll
    for (int mi = 0; mi < 4; mi++) {
#pragma unroll
        for (int ni = 0; ni < 4; ni++) {
            int gm = m0 + wm * 64 + mi * 16 + quad * 4;
            int gn = n0 + wn * 64 + ni * 16 + lrow;
            if constexpr (OUTM == 0) {
                unsigned short* C = (unsigned short*)Call + (size_t)b * cStride;
#pragma unroll
                for (int r = 0; r < 4; r++)
                    C[(size_t)(gm + r) * ldc + gn] = f2h(acc[mi][ni][r]);
            } else if constexpr (OUTM == 1) {
                unsigned short* C = (unsigned short*)Call + (size_t)b * cStride;
                const int* mk = maskAll + (size_t)b * maskStride;
                bool keep = mk[gn] != 0;
#pragma unroll
                for (int r = 0; r < 4; r++)
                    C[(size_t)(gm + r) * ldc + gn] =
                        keep ? f2h(acc[mi][ni][r] * scale) : f2h(-60000.f);
            } else {
                float* C = (float*)Call + (size_t)b * cStride;
#pragma unroll
                for (int r = 0; r < 4; r++)
                    C[(size_t)(gm + r) * ldc + gn] = acc[mi][ni][r];
            }
        }
    }
}

// ---------------------------------------------------------------------------
// Row softmax: read f16 scores, write fp32 dist (output) + normalized f16
// in place (context-GEMM input). One block per row of 2048.
// ---------------------------------------------------------------------------
__global__ __launch_bounds__(256) void softmax_rows(unsigned short* __restrict__ sc,
                                                    float* __restrict__ dist) {
    unsigned short* sp = sc + (size_t)blockIdx.x * 2048;
    float* dp = dist + (size_t)blockIdx.x * 2048;
    int tid = threadIdx.x;

    uint4 u = *(uint4*)(sp + tid * 8);
    float x[8];
    x[0] = h2f((unsigned short)(u.x & 0xffff)); x[1] = h2f((unsigned short)(u.x >> 16));
    x[2] = h2f((unsigned short)(u.y & 0xffff)); x[3] = h2f((unsigned short)(u.y >> 16));
    x[4] = h2f((unsigned short)(u.z & 0xffff)); x[5] = h2f((unsigned short)(u.z >> 16));
    x[6] = h2f((unsigned short)(u.w & 0xffff)); x[7] = h2f((unsigned short)(u.w >> 16));

    float m = x[0];
#pragma unroll
    for (int i = 1; i < 8; i++) m = fmaxf(m, x[i]);
#pragma unroll
    for (int off = 32; off > 0; off >>= 1) m = fmaxf(m, __shfl_down(m, off));

    __shared__ float red[8];
    if ((tid & 63) == 0) red[tid >> 6] = m;
    __syncthreads();
    m = fmaxf(fmaxf(red[0], red[1]), fmaxf(red[2], red[3]));

    float s = 0.f;
#pragma unroll
    for (int i = 0; i < 8; i++) { x[i] = __expf(x[i] - m); s += x[i]; }
#pragma unroll
    for (int off = 32; off > 0; off >>= 1) s += __shfl_down(s, off);
    if ((tid & 63) == 0) red[4 + (tid >> 6)] = s;
    __syncthreads();
    float inv = 1.0f / (red[4] + red[5] + red[6] + red[7]);

#pragma unroll
    for (int i = 0; i < 8; i++) x[i] *= inv;

    float4 o0 = {x[0], x[1], x[2], x[3]};
    float4 o1 = {x[4], x[5], x[6], x[7]};
    *(float4*)(dp + tid * 8) = o0;
    *(float4*)(dp + tid * 8 + 4) = o1;

    uint4 v;
    v.x = (unsigned)f2h(x[0]) | ((unsigned)f2h(x[1]) << 16);
    v.y = (unsigned)f2h(x[2]) | ((unsigned)f2h(x[3]) << 16);
    v.z = (unsigned)f2h(x[4]) | ((unsigned)f2h(x[5]) << 16);
    v.w = (unsigned)f2h(x[6]) | ((unsigned)f2h(x[7]) << 16);
    *(uint4*)(sp + tid * 8) = v;
}

// ---------------------------------------------------------------------------
extern "C" void kernel_launch(void* const* d_in, const int* in_sizes, int n_in,
                              void* d_out, int out_size, void* d_ws, size_t ws_size,
                              hipStream_t stream) {
    const float* q    = (const float*)d_in[0];   // [B,Q,D]
    const float* k    = (const float*)d_in[1];   // [B,K,D]
    const float* v    = (const float*)d_in[2];   // [B,K,D]
    const int*   mask = (const int*)d_in[3];     // [B,K]
    const float* W    = (const float*)d_in[4];   // [D,D]

    float* ctx  = (float*)d_out;                           // [B,Q,D]
    float* dist = ctx + (size_t)BB * QQ * DD;              // [B,Q,K]

    // workspace layout (f16 = unsigned short), total ~118 MiB
    unsigned short* ws  = (unsigned short*)d_ws;
    unsigned short* Wt  = ws;                                   // [D][D]   (W^T)
    unsigned short* Kh  = Wt + (size_t)DD * DD;                 // [B][K][D]
    unsigned short* Vt  = Kh + (size_t)BB * KK * DD;            // [B][D][K] (V^T)
    unsigned short* qWh = Vt + (size_t)BB * DD * KK;            // [B][Q][D]
    unsigned short* Sc  = qWh + (size_t)BB * QQ * DD;           // [B][Q][K] scores/dist f16

    const float scale = 0.044194173824159216f;  // 1/sqrt(512)

    // 1) W -> W^T f16
    transpose_cvt<<<dim3(DD / 32, DD / 32, 1), 256, 0, stream>>>(W, Wt, DD, DD, 0, 0);
    // 2) key -> f16
    cvt_f32_f16<<<dim3((BB * KK * DD / 8) / 256), 256, 0, stream>>>(k, Kh);
    // 3) value -> V^T f16
    transpose_cvt<<<dim3(DD / 32, KK / 32, BB), 256, 0, stream>>>(
        v, Vt, KK, DD, (long)KK * DD, (long)DD * KK);
    // 4) qW[b] = Q[b] @ W (A fp32 staged-converted): M=Q, N=D, Kred=D -> f16
    gemm_bt<true, 0><<<dim3(DD / 128, QQ / 128, BB), 256, 0, stream>>>(
        q, Wt, qWh, nullptr, DD, DD, DD, DD,
        (long)QQ * DD, 0, (long)QQ * DD, 0, 0.f);
    // 5) scores[b] = qW[b] @ key[b]^T, mask+scale -> Sc (f16)
    gemm_bt<false, 1><<<dim3(KK / 128, QQ / 128, BB), 256, 0, stream>>>(
        qWh, Kh, Sc, mask, DD, DD, DD, KK,
        (long)QQ * DD, (long)KK * DD, (long)QQ * KK, KK, scale);
    // 6) softmax rows: Sc f16 -> dist fp32 + Sc normalized f16 in place
    softmax_rows<<<dim3(BB * QQ), 256, 0, stream>>>(Sc, dist);
    // 7) context[b] = dist[b] @ value[b] (NT with Vt): M=Q, N=D, Kred=K
    gemm_bt<false, 2><<<dim3(DD / 128, QQ / 128, BB), 256, 0, stream>>>(
        Sc, Vt, ctx, nullptr, KK, KK, KK, DD,
        (long)QQ * KK, (long)DD * KK, (long)QQ * DD, 0, 0.f);
}

// Round 3
// 420.950 us; speedup vs baseline: 1.1045x; 1.0099x over previous
//
#include <hip/hip_runtime.h>
#include <stdint.h>

// Problem constants (reference: B=8, Q=2048, K=2048, D=512)
#define BB 8
#define QQ 2048
#define KK 2048
#define DD 512

typedef _Float16 f16x8 __attribute__((ext_vector_type(8)));
typedef float f32x4 __attribute__((ext_vector_type(4)));

__device__ __forceinline__ unsigned short f2h(float f) {
    union { _Float16 h; unsigned short u; } x;
    x.h = (_Float16)f;
    return x.u;
}
__device__ __forceinline__ float h2f(unsigned short u) {
    union { unsigned short u; _Float16 h; } x;
    x.u = u;
    return (float)x.h;
}

// async global->LDS, 16 B per lane; lds is wave-uniform base, HW scatters
// lane l to lds + l*16 (m97/m104 semantics).
__device__ __forceinline__ void async16(const unsigned short* g, unsigned short* l) {
    __builtin_amdgcn_global_load_lds(
        (const __attribute__((address_space(1))) unsigned int*)g,
        (__attribute__((address_space(3))) unsigned int*)l, 16, 0, 0);
}

// ---------------------------------------------------------------------------
// fp32 -> fp16 convert, 8 elems/thread
// ---------------------------------------------------------------------------
__global__ __launch_bounds__(256) void cvt_f32_f16(const float* __restrict__ in,
                                                   unsigned short* __restrict__ out) {
    size_t i = ((size_t)blockIdx.x * 256 + threadIdx.x) * 8;
    float4 a = *(const float4*)(in + i);
    float4 b = *(const float4*)(in + i + 4);
    uint4 u;
    u.x = (unsigned)f2h(a.x) | ((unsigned)f2h(a.y) << 16);
    u.y = (unsigned)f2h(a.z) | ((unsigned)f2h(a.w) << 16);
    u.z = (unsigned)f2h(b.x) | ((unsigned)f2h(b.y) << 16);
    u.w = (unsigned)f2h(b.z) | ((unsigned)f2h(b.w) << 16);
    *(uint4*)(out + i) = u;
}

// ---------------------------------------------------------------------------
// Tiled transpose + convert: in[R][C] fp32 -> out[C][R] fp16 (32x32 tiles)
// ---------------------------------------------------------------------------
__global__ __launch_bounds__(256) void transpose_cvt(const float* __restrict__ in,
                                                     unsigned short* __restrict__ out,
                                                     int R, int C, long inB, long outB) {
    __shared__ float t[32][33];
    const float* ip = in + (size_t)blockIdx.z * inB;
    unsigned short* op = out + (size_t)blockIdx.z * outB;
    int x = threadIdx.x & 31, y0 = threadIdx.x >> 5;   // 32 x 8
    int c0 = blockIdx.x * 32, r0 = blockIdx.y * 32;
#pragma unroll
    for (int i = 0; i < 32; i += 8)
        t[y0 + i][x] = ip[(size_t)(r0 + y0 + i) * C + c0 + x];
    __syncthreads();
#pragma unroll
    for (int i = 0; i < 32; i += 8)
        op[(size_t)(c0 + y0 + i) * R + r0 + x] = f2h(t[x][y0 + i]);
}

// ---------------------------------------------------------------------------
// NT GEMM: C[m,n] = sum_k A[m,k]*B[n,k], 128x128 tile, BK=32, f16 MFMA,
// async global_load_lds staging on both operands.
// OUTM 0: plain f16 out (qW)
// OUTM 1: expS epilogue: e = mask ? exp(acc*scale) : 0 -> f16 out,
//         per-row sums accumulated into `sums` via atomicAdd (scores)
// OUTM 2: fp32 out, scaled by 1/sums[row]  (context)
// ---------------------------------------------------------------------------
template <int OUTM>
__global__ __launch_bounds__(256) void gemm_bt(const unsigned short* __restrict__ Aall,
                                               const unsigned short* __restrict__ Ball,
                                               void* __restrict__ Call,
                                               const int* __restrict__ maskAll,
                                               float* __restrict__ sums,
                                               int Kred, int lda, int ldb, int ldc,
                                               long aStride, long bStride, long cStride,
                                               int maskStride, float scale) {
    const int b = blockIdx.z;
    const int m0 = blockIdx.y * 128;
    const int n0 = blockIdx.x * 128;

    __shared__ unsigned short As[128 * 32];
    __shared__ unsigned short Bs[128 * 32];

    const int tid = threadIdx.x;
    const int lane = tid & 63, wave = tid >> 6;
    const int wm = wave >> 1, wn = wave & 1;
    const int lrow = lane & 15, quad = lane >> 4;

    // async staging: call j covers rows j*64 + tid>>2, col (tid&3)*8 (16 B)
    const int ar = tid >> 2, ac = (tid & 3) * 8;

    const unsigned short* Ab = Aall + (size_t)b * aStride + (size_t)m0 * lda;
    const unsigned short* Bb = Ball + (size_t)b * bStride + (size_t)n0 * ldb;
    unsigned short* AsW = As + wave * 512;   // wave-uniform async dst
    unsigned short* BsW = Bs + wave * 512;

    f32x4 acc[4][4];
#pragma unroll
    for (int mi = 0; mi < 4; mi++)
#pragma unroll
        for (int ni = 0; ni < 4; ni++)
            acc[mi][ni] = (f32x4){0.f, 0.f, 0.f, 0.f};

    for (int kk = 0; kk < Kred; kk += 32) {
#pragma unroll
        for (int j = 0; j < 2; j++)
            async16(Ab + (size_t)(j * 64 + ar) * lda + kk + ac, AsW + j * 2048);
#pragma unroll
        for (int j = 0; j < 2; j++)
            async16(Bb + (size_t)(j * 64 + ar) * ldb + kk + ac, BsW + j * 2048);
        __syncthreads();

        f16x8 af[4], bfr[4];
#pragma unroll
        for (int i = 0; i < 4; i++)
            af[i] = *(const f16x8*)&As[(wm * 64 + i * 16 + lrow) * 32 + quad * 8];
#pragma unroll
        for (int i = 0; i < 4; i++)
            bfr[i] = *(const f16x8*)&Bs[(wn * 64 + i * 16 + lrow) * 32 + quad * 8];

#pragma unroll
        for (int mi = 0; mi < 4; mi++)
#pragma unroll
            for (int ni = 0; ni < 4; ni++)
                acc[mi][ni] = __builtin_amdgcn_mfma_f32_16x16x32_f16(af[mi], bfr[ni],
                                                                     acc[mi][ni], 0, 0, 0);
        __syncthreads();
    }

    // ---- epilogue ----
#pragma unroll
    for (int mi = 0; mi < 4; mi++) {
        const int gm = m0 + wm * 64 + mi * 16 + quad * 4;
        if constexpr (OUTM == 0) {
            unsigned short* C = (unsigned short*)Call + (size_t)b * cStride;
#pragma unroll
            for (int ni = 0; ni < 4; ni++) {
                int gn = n0 + wn * 64 + ni * 16 + lrow;
#pragma unroll
                for (int r = 0; r < 4; r++)
                    C[(size_t)(gm + r) * ldc + gn] = f2h(acc[mi][ni][r]);
            }
        } else if constexpr (OUTM == 1) {
            unsigned short* C = (unsigned short*)Call + (size_t)b * cStride;
            const int* mk = maskAll + (size_t)b * maskStride;
            float ps[4] = {0.f, 0.f, 0.f, 0.f};
#pragma unroll
            for (int ni = 0; ni < 4; ni++) {
                int gn = n0 + wn * 64 + ni * 16 + lrow;
                bool keep = mk[gn] != 0;
#pragma unroll
                for (int r = 0; r < 4; r++) {
                    float e = keep ? __expf(acc[mi][ni][r] * scale) : 0.f;
                    C[(size_t)(gm + r) * ldc + gn] = f2h(e);
                    ps[r] += e;
                }
            }
            // reduce across the 16 lanes sharing this quad's rows
#pragma unroll
            for (int off = 1; off < 16; off <<= 1)
#pragma unroll
                for (int r = 0; r < 4; r++) ps[r] += __shfl_xor(ps[r], off);
            if (lrow == 0) {
                float* s = sums + (size_t)b * QQ;
#pragma unroll
                for (int r = 0; r < 4; r++) atomicAdd(&s[gm + r], ps[r]);
            }
        } else {
            float* C = (float*)Call + (size_t)b * cStride;
            const float* s = sums + (size_t)b * QQ;
            float iv[4];
#pragma unroll
            for (int r = 0; r < 4; r++) iv[r] = 1.0f / s[gm + r];
#pragma unroll
            for (int ni = 0; ni < 4; ni++) {
                int gn = n0 + wn * 64 + ni * 16 + lrow;
#pragma unroll
                for (int r = 0; r < 4; r++)
                    C[(size_t)(gm + r) * ldc + gn] = acc[mi][ni][r] * iv[r];
            }
        }
    }
}

// ---------------------------------------------------------------------------
// dist[row,:] = expS[row,:] * (1/sums[row]).  One block per row of 2048.
// ---------------------------------------------------------------------------
__global__ __launch_bounds__(256) void normalize_rows(const unsigned short* __restrict__ expS,
                                                      const float* __restrict__ sums,
                                                      float* __restrict__ dist) {
    const unsigned short* sp = expS + (size_t)blockIdx.x * 2048;
    float* dp = dist + (size_t)blockIdx.x * 2048;
    const float inv = 1.0f / sums[blockIdx.x];
    int tid = threadIdx.x;

    uint4 u = *(const uint4*)(sp + tid * 8);
    float4 o0, o1;
    o0.x = h2f((unsigned short)(u.x & 0xffff)) * inv;
    o0.y = h2f((unsigned short)(u.x >> 16)) * inv;
    o0.z = h2f((unsigned short)(u.y & 0xffff)) * inv;
    o0.w = h2f((unsigned short)(u.y >> 16)) * inv;
    o1.x = h2f((unsigned short)(u.z & 0xffff)) * inv;
    o1.y = h2f((unsigned short)(u.z >> 16)) * inv;
    o1.z = h2f((unsigned short)(u.w & 0xffff)) * inv;
    o1.w = h2f((unsigned short)(u.w >> 16)) * inv;
    *(float4*)(dp + tid * 8) = o0;
    *(float4*)(dp + tid * 8 + 4) = o1;
}

// ---------------------------------------------------------------------------
extern "C" void kernel_launch(void* const* d_in, const int* in_sizes, int n_in,
                              void* d_out, int out_size, void* d_ws, size_t ws_size,
                              hipStream_t stream) {
    const float* q    = (const float*)d_in[0];   // [B,Q,D]
    const float* k    = (const float*)d_in[1];   // [B,K,D]
    const float* v    = (const float*)d_in[2];   // [B,K,D]
    const int*   mask = (const int*)d_in[3];     // [B,K]
    const float* W    = (const float*)d_in[4];   // [D,D]

    float* ctx  = (float*)d_out;                           // [B,Q,D]
    float* dist = ctx + (size_t)BB * QQ * DD;              // [B,Q,K]

    // workspace layout (f16 = unsigned short), ~135 MiB
    unsigned short* ws  = (unsigned short*)d_ws;
    unsigned short* Wt  = ws;                                   // [D][D]   (W^T)
    unsigned short* Qh  = Wt + (size_t)DD * DD;                 // [B][Q][D]
    unsigned short* Kh  = Qh + (size_t)BB * QQ * DD;            // [B][K][D]
    unsigned short* Vt  = Kh + (size_t)BB * KK * DD;            // [B][D][K] (V^T)
    unsigned short* qWh = Vt + (size_t)BB * DD * KK;            // [B][Q][D]
    unsigned short* Sc  = qWh + (size_t)BB * QQ * DD;           // [B][Q][K] expS f16
    float* sums = (float*)(Sc + (size_t)BB * QQ * KK);          // [B][Q]

    const float scale = 0.044194173824159216f;  // 1/sqrt(512)

    // 0) zero the row-sum accumulators (graph-capture-legal async memset)
    hipMemsetAsync(sums, 0, (size_t)BB * QQ * sizeof(float), stream);
    // 1) W -> W^T f16
    transpose_cvt<<<dim3(DD / 32, DD / 32, 1), 256, 0, stream>>>(W, Wt, DD, DD, 0, 0);
    // 2) query, key -> f16
    cvt_f32_f16<<<dim3((BB * QQ * DD / 8) / 256), 256, 0, stream>>>(q, Qh);
    cvt_f32_f16<<<dim3((BB * KK * DD / 8) / 256), 256, 0, stream>>>(k, Kh);
    // 3) value -> V^T f16
    transpose_cvt<<<dim3(DD / 32, KK / 32, BB), 256, 0, stream>>>(
        v, Vt, KK, DD, (long)KK * DD, (long)DD * KK);
    // 4) qW[b] = Q[b] @ W: M=Q, N=D, Kred=D -> f16
    gemm_bt<0><<<dim3(DD / 128, QQ / 128, BB), 256, 0, stream>>>(
        Qh, Wt, qWh, nullptr, nullptr, DD, DD, DD, DD,
        (long)QQ * DD, 0, (long)QQ * DD, 0, 0.f);
    // 5) expS[b] = exp(scale * qW[b] @ key[b]^T) (masked->0) + row sums
    gemm_bt<1><<<dim3(KK / 128, QQ / 128, BB), 256, 0, stream>>>(
        qWh, Kh, Sc, mask, sums, DD, DD, DD, KK,
        (long)QQ * DD, (long)KK * DD, (long)QQ * KK, KK, scale);
    // 6) dist = expS / rowsum  (fp32 output)
    normalize_rows<<<dim3(BB * QQ), 256, 0, stream>>>(Sc, sums, dist);
    // 7) context[b] = (expS[b] @ value[b]) / rowsum: M=Q, N=D, Kred=K
    gemm_bt<2><<<dim3(DD / 128, QQ / 128, BB), 256, 0, stream>>>(
        Sc, Vt, ctx, nullptr, sums, KK, KK, KK, DD,
        (long)QQ * KK, (long)DD * KK, (long)QQ * DD, 0, 0.f);
}